// Round 5
// baseline (313.075 us; speedup 1.0000x reference)
//
#include <hip/hip_runtime.h>

typedef unsigned short u16;
typedef __attribute__((ext_vector_type(8))) short bf16x8;
typedef __attribute__((ext_vector_type(4))) float f32x4;
typedef __attribute__((ext_vector_type(8))) unsigned short u16x8;

#define MFMA16(a, b, c) __builtin_amdgcn_mfma_f32_16x16x32_bf16((a), (b), (c), 0, 0, 0)

// d_ws layout (u16 element offsets). All operands PRE-PACKED in per-fragment
// order so every B-load in k_fused is a wave-contiguous 1KB burst.
//   dense W, 16-col group g, k-step kk: elem (((g>>1)*8+kk)*2+(g&1))*512 + lane*8 + j
//            <- W[g*16 + (lane&15)][kk*32 + ((lane>>4)&3)*8 + j]
//   Wc1, col-group cw (0..7): elem ((cw*8+kk)*512) + lane*8 + j
//   KN/VT (per head h): elem (((h*2+kk)*4+nt)*512) + lane*8 + j
#define OFF_WQ   0
#define OFF_WG   65536
#define OFF_WC1  131072
#define OFF_WO   163840
#define OFF_KNF  229376
#define OFF_VTF  245760
#define OFF_KND  262144
#define OFF_VTD  278528

__device__ __forceinline__ u16 f2b(float f) {
  union { float f; unsigned u; } v; v.f = f;
  unsigned r = v.u + 0x7fffu + ((v.u >> 16) & 1u);  // RNE fp32->bf16
  return (u16)(r >> 16);
}
__device__ __forceinline__ unsigned pk2(float lo, float hi) {  // 2x f32 -> packed bf16 (RNE)
  unsigned r;
  asm("v_cvt_pk_bf16_f32 %0, %1, %2" : "=v"(r) : "v"(lo), "v"(hi));
  return r;
}
__device__ __forceinline__ float fsig(float x) {
  return __builtin_amdgcn_rcpf(1.f + __expf(-x));
}
__device__ __forceinline__ float ftanh(float x) {
  float e = __expf(2.f * x);
  return (e - 1.f) * __builtin_amdgcn_rcpf(e + 1.f);
}
__device__ __forceinline__ float sum16(float v) {
  v += __shfl_xor(v, 1);
  v += __shfl_xor(v, 2);
  v += __shfl_xor(v, 4);
  v += __shfl_xor(v, 8);
  return v;
}

// ---------- pre-kernel: convert+pack weights; norm/pack keys; transpose/pack vals ----------
__global__ void k_prep(const float* __restrict__ Wq, const float* __restrict__ Wg,
                       const float* __restrict__ Wc1, const float* __restrict__ Wo,
                       const float* __restrict__ fk, const float* __restrict__ fv,
                       const float* __restrict__ dk, const float* __restrict__ dv,
                       u16* __restrict__ ws) {
  const int bid = blockIdx.x, t = threadIdx.x;
  if (bid < 96) {  // Wq/Wg/Wo: 8192 16B-chunks each, 32 blocks each
    const float* W = bid < 32 ? Wq : (bid < 64 ? Wg : Wo);
    const int OFF = bid < 32 ? OFF_WQ : (bid < 64 ? OFF_WG : OFF_WO);
    int c = (bid & 31) * 256 + t;
    int lane = c & 63, nt = (c >> 6) & 1, kk = (c >> 7) & 7, w = c >> 10;
    const float* s = W + (w * 32 + nt * 16 + (lane & 15)) * 256 + kk * 32 + ((lane >> 4) & 3) * 8;
    u16x8 o;
    #pragma unroll
    for (int j = 0; j < 8; ++j) o[j] = f2b(s[j]);
    *(u16x8*)(ws + OFF + c * 8) = o;
  } else if (bid < 112) {  // Wc1: 4096 chunks, 16 blocks
    int c = (bid - 96) * 256 + t;
    int lane = c & 63, kk = (c >> 6) & 7, w = c >> 9;
    const float* s = Wc1 + (w * 16 + (lane & 15)) * 256 + kk * 32 + ((lane >> 4) & 3) * 8;
    u16x8 o;
    #pragma unroll
    for (int j = 0; j < 8; ++j) o[j] = f2b(s[j]);
    *(u16x8*)(ws + OFF_WC1 + c * 8) = o;
  } else {  // keys/vals: 1024 (structure,row) units, one wave each
    int unit = (bid - 112) * 4 + (t >> 6);
    int lane = t & 63;
    int st = unit >> 8, rowid = unit & 255;
    int hh = rowid >> 6, s = rowid & 63;
    if (st < 2) {  // keys: coalesced load, wave-reduce norm, 1 scattered store/lane
      const float* p = (st == 0 ? fk : dk) + rowid * 64;
      float x = p[lane];
      float v = x * x;
      v += __shfl_xor(v, 1);  v += __shfl_xor(v, 2);  v += __shfl_xor(v, 4);
      v += __shfl_xor(v, 8);  v += __shfl_xor(v, 16); v += __shfl_xor(v, 32);
      float sc = __builtin_amdgcn_rcpf(__builtin_amdgcn_sqrtf(v) + 1e-8f);
      int nt = s >> 4, kk = lane >> 5, lo = ((lane >> 3) & 3) * 16 + (s & 15), j = lane & 7;
      ws[(st == 0 ? OFF_KNF : OFF_KND) + (((hh * 2 + kk) * 4 + nt) * 64 + lo) * 8 + j] =
          f2b(x * sc);
    } else {  // vals: transpose scatter, 1 store/lane
      const float* p = (st == 2 ? fv : dv) + rowid * 64;
      int kk = s >> 5, qd = (s >> 3) & 3, j = s & 7;
      int lo = qd * 16 + (lane & 15), nt = lane >> 4;
      ws[(st == 2 ? OFF_VTF : OFF_VTD) + (((hh * 2 + kk) * 4 + nt) * 64 + lo) * 8 + j] =
          f2b(p[lane]);
    }
  }
}

// ---------- fused main kernel ----------
// 512 blocks x 1024 threads (16 waves); 128 rows/block (2x arithmetic intensity
// per weight-fragment vs 64-row blocks -> ws L2/L3 traffic halves).
// gate/conf/Wq/Wo: wave w owns 16 output cols (col-split; Wq col-split cuts its
// fragment traffic 4x vs head-split, q-norm via cross-wave red_q).
// Attention: wave w owns head hd=w&3, rows rb=(w>>2)*32..+31; the two 16-row
// halves share KN/VT B-frags (loaded once per tier); tiers sequential (no spill).
__global__ __launch_bounds__(1024, 4)
void k_fused(const float* __restrict__ query, const float* __restrict__ context,
             const float* __restrict__ bq, const float* __restrict__ bg,
             const float* __restrict__ bc1, const float* __restrict__ Wc2,
             const float* __restrict__ bc2v, const float* __restrict__ bo,
             const float* __restrict__ mixl, const u16* __restrict__ ws,
             float* __restrict__ outp) {
  extern __shared__ char smem[];
  char* Xb = smem;                              // 64 KB: ctx -> 16 wave chunks (4KB: q,P)
  char* Yb = smem + 65536;                      // 64 KB: query -> out_pre
  float* red_a = (float*)(smem + 131072);       // [128][16] gate partials
  float* red_c = (float*)(smem + 139264);       // [128][8]  conf partials
  float* red_q = (float*)(smem + 143360);       // [128][16] q-norm ss partials
  float* sA    = (float*)(smem + 151552);       // [128] conf*mix
  float* sB    = (float*)(smem + 152064);       // [128] conf*(1-mix)

  const int t = threadIdx.x;
  const int w = t >> 6;
  const int lane = t & 63;
  const int quad = lane >> 4;
  const int l16 = lane & 15;
  const int row4 = quad * 4;
  const int l16e = l16 & ~1;
  const int oddl = lane & 1;
  const int hd = w & 3;             // attention reader: head
  const int rb = (w >> 2) * 32;     // attention reader: row base
  const int hdc = w >> 2;           // q-writer: head of owned cols
  const int cg = w & 3;             // q-writer: 16-col group within head
  const int blk = blockIdx.x;
  char* Ch = Xb + w * 4096;         // this wave's attention chunk (32x64 bf16, swizzled)

  auto stage = [&](char* dstB, const float* src) {
    #pragma unroll
    for (int i = 0; i < 8; ++i) {
      int e = i * 4096 + t * 4;
      float4 v = *(const float4*)(src + e);
      int row = e >> 8, col = e & 255;
      uint2 pk;
      pk.x = pk2(v.x, v.y);
      pk.y = pk2(v.z, v.w);
      *(uint2*)(dstB + row * 512 + ((((col >> 3) ^ (row & 7)) << 4) | ((col & 7) << 1))) = pk;
    }
  };
  auto ldA = [&](const char* B, int row, int kb) {  // A-frag: m=row, k=kb..kb+7
    return *(const bf16x8*)(B + row * 512 + ((((kb >> 3) ^ (row & 7)) << 4)));
  };
  auto ldCh = [&](int row, int kb) {  // A-frag from own chunk (32 rows)
    return *(const bf16x8*)(Ch + row * 128 + ((((kb >> 3) ^ (row & 7)) << 4)));
  };
  auto wfrag = [&](int OFF, int g, int kk) {  // dense-W B-frag, 16-col group g
    return *(const bf16x8*)(ws + OFF + ((((g >> 1) * 8 + kk) * 2 + (g & 1)) * 64 + lane) * 8);
  };
  // packed pair-lane b32 write of 4 values at cols {nt*16+l16} into own chunk
  auto st4c = [&](int row, float v0, float v1, float v2, float v3) {
    float o0 = __shfl_xor(v0, 1), o1 = __shfl_xor(v1, 1);
    float o2 = __shfl_xor(v2, 1), o3 = __shfl_xor(v3, 1);
    float lo0 = oddl ? o1 : v0, hi0 = oddl ? v1 : o0;
    float lo1 = oddl ? o3 : v2, hi1 = oddl ? v3 : o2;
    int c0 = (oddl ? 16 : 0) + l16e, c1 = (oddl ? 48 : 32) + l16e;
    *(unsigned*)(Ch + row * 128 + ((((c0 >> 3) ^ (row & 7)) << 4) | ((c0 & 7) << 1))) = pk2(lo0, hi0);
    *(unsigned*)(Ch + row * 128 + ((((c1 >> 3) ^ (row & 7)) << 4) | ((c1 & 7) << 1))) = pk2(lo1, hi1);
  };
  auto st4y = [&](int row, int cb, float v0, float v1, float v2, float v3) {
    float o0 = __shfl_xor(v0, 1), o1 = __shfl_xor(v1, 1);
    float o2 = __shfl_xor(v2, 1), o3 = __shfl_xor(v3, 1);
    float lo0 = oddl ? o1 : v0, hi0 = oddl ? v1 : o0;
    float lo1 = oddl ? o3 : v2, hi1 = oddl ? v3 : o2;
    int c0 = cb + (oddl ? 16 : 0) + l16e, c1 = cb + (oddl ? 48 : 32) + l16e;
    *(unsigned*)(Yb + row * 512 + ((((c0 >> 3) ^ (row & 7)) << 4) | ((c0 & 7) << 1))) = pk2(lo0, hi0);
    *(unsigned*)(Yb + row * 512 + ((((c1 >> 3) ^ (row & 7)) << 4) | ((c1 & 7) << 1))) = pk2(lo1, hi1);
  };

  const f32x4 vzero = {0.f, 0.f, 0.f, 0.f};

  // ===== entry: stage BOTH inputs (128 rows each); hoist small params =====
  stage(Xb, context + (size_t)blk * 32768);
  stage(Yb, query + (size_t)blk * 32768);
  float bgv  = bg[w * 16 + l16];
  float bov  = bo[w * 16 + l16];
  float bqv  = bq[w * 16 + l16];
  float bc1v = bc1[(w & 7) * 16 + l16];
  float wc2v = Wc2[(w & 7) * 16 + l16];
  __syncthreads();  // bar1: both stages complete

  // ===== gate GEMM on X: wave w -> cols w*16..+15, rows 0..127 =====
  {
    f32x4 ag[8];
    #pragma unroll
    for (int mt = 0; mt < 8; ++mt) ag[mt] = vzero;
    #pragma unroll
    for (int kk = 0; kk < 8; ++kk) {
      int kb = kk * 32 + quad * 8;
      bf16x8 b = wfrag(OFF_WG, w, kk);
      #pragma unroll
      for (int mt = 0; mt < 8; ++mt) {
        bf16x8 a = ldA(Xb, mt * 16 + l16, kb);
        ag[mt] = MFMA16(a, b, ag[mt]);
      }
    }
    #pragma unroll
    for (int mt = 0; mt < 8; ++mt)
      #pragma unroll
      for (int r = 0; r < 4; ++r) {
        float sg = sum16(ftanh(ag[mt][r] + bgv));
        if (l16 == 0) red_a[(mt * 16 + row4 + r) * 16 + w] = sg;
      }
  }
  // ===== conf GEMM on X: col-group w&7; waves 0-7 rows 0..63, 8-15 rows 64..127 =====
  {
    const int mtb = (w < 8) ? 0 : 4;
    f32x4 ac[4];
    #pragma unroll
    for (int m = 0; m < 4; ++m) ac[m] = vzero;
    #pragma unroll
    for (int kk = 0; kk < 8; ++kk) {
      int kb = kk * 32 + quad * 8;
      bf16x8 b = *(const bf16x8*)(ws + OFF_WC1 + (((w & 7) * 8 + kk) * 64 + lane) * 8);
      #pragma unroll
      for (int m = 0; m < 4; ++m) {
        bf16x8 a = ldA(Xb, (mtb + m) * 16 + l16, kb);
        ac[m] = MFMA16(a, b, ac[m]);
      }
    }
    #pragma unroll
    for (int m = 0; m < 4; ++m)
      #pragma unroll
      for (int r = 0; r < 4; ++r) {
        float sc = sum16(ftanh(ac[m][r] + bc1v) * wc2v);
        if (l16 == 0) red_c[((mtb + m) * 16 + row4 + r) * 8 + (w & 7)] = sc;
      }
  }
  __syncthreads();  // bar2: partials published; X reads done (chunks may be written)

  // ===== waves 0,1 combine mix/conf; all waves: Wq GEMM on Y (col-split) =====
  if (t < 128) {
    float g = 0.f, cc = 0.f;
    #pragma unroll
    for (int i = 0; i < 4; ++i) {
      f32x4 v = *(const f32x4*)(red_a + t * 16 + i * 4);
      g += v[0] + v[1] + v[2] + v[3];
    }
    #pragma unroll
    for (int i = 0; i < 2; ++i) {
      f32x4 v = *(const f32x4*)(red_c + t * 8 + i * 4);
      cc += v[0] + v[1] + v[2] + v[3];
    }
    float mix = fsig(mixl[0] + g * (1.f / 256.f));
    float conf = fsig(cc + bc2v[0]);
    sA[t] = conf * mix;
    sB[t] = conf - conf * mix;
  }
  f32x4 qa[8];
  {
    #pragma unroll
    for (int mt = 0; mt < 8; ++mt) qa[mt] = vzero;
    #pragma unroll
    for (int kk = 0; kk < 8; ++kk) {
      int kb = kk * 32 + quad * 8;
      bf16x8 b = wfrag(OFF_WQ, w, kk);
      #pragma unroll
      for (int mt = 0; mt < 8; ++mt) {
        bf16x8 a = ldA(Yb, mt * 16 + l16, kb);
        qa[mt] = MFMA16(a, b, qa[mt]);
      }
    }
    #pragma unroll
    for (int mt = 0; mt < 8; ++mt)
      #pragma unroll
      for (int r = 0; r < 4; ++r) {
        float q_ = qa[mt][r] + bqv;
        qa[mt][r] = q_;
        float ss = sum16(q_ * q_);
        if (l16 == 0) red_q[(mt * 16 + row4 + r) * 16 + w] = ss;
      }
  }
  __syncthreads();  // bar3: red_q published; all Y reads done

  // ===== q-norm scale + scatter q into per-(rowgrp,head) chunks =====
  #pragma unroll
  for (int mt = 0; mt < 8; ++mt)
    #pragma unroll
    for (int r = 0; r < 4; ++r) {
      int R = mt * 16 + row4 + r;
      f32x4 p4 = *(const f32x4*)(red_q + R * 16 + hdc * 4);  // quad-broadcast read
      float ss = p4[0] + p4[1] + p4[2] + p4[3];
      float scl = __builtin_amdgcn_rcpf(__builtin_amdgcn_sqrtf(ss) + 1e-8f);
      char* cb = Xb + (((R >> 5) * 4 + hdc) << 12);
      int col = cg * 16 + l16, rr = R & 31;
      *(u16*)(cb + rr * 128 + ((((col >> 3) ^ (rr & 7)) << 4) | ((col & 7) << 1))) =
          f2b(qa[mt][r] * scl);
    }
  __syncthreads();  // bar4: chunks (q) ready; sA/sB ready

  // ===== attention: wave-local; halves share B-frags; tiers sequential =====
  bf16x8 qf[2][2];  // q A-frags for both halves, held across both tiers
  #pragma unroll
  for (int h = 0; h < 2; ++h)
    #pragma unroll
    for (int kq = 0; kq < 2; ++kq)
      qf[h][kq] = ldCh(h * 16 + l16, kq * 32 + quad * 8);

  f32x4 oa[2][4];
  #pragma unroll
  for (int tier = 0; tier < 2; ++tier) {
    const u16* KN = ws + (tier == 0 ? OFF_KNF : OFF_KND);
    const u16* VT = ws + (tier == 0 ? OFF_VTF : OFF_VTD);

    // QK^T for both halves off one B-frag load (cos sims bounded -> no max-sub)
    f32x4 s4[2][4];
    #pragma unroll
    for (int h = 0; h < 2; ++h)
      #pragma unroll
      for (int nt = 0; nt < 4; ++nt) s4[h][nt] = vzero;
    #pragma unroll
    for (int kk = 0; kk < 2; ++kk)
      #pragma unroll
      for (int nt = 0; nt < 4; ++nt) {
        bf16x8 b = *(const bf16x8*)(KN + (((hd * 2 + kk) * 4 + nt) * 64 + lane) * 8);
        s4[0][nt] = MFMA16(qf[0][kk], b, s4[0][nt]);
        s4[1][nt] = MFMA16(qf[1][kk], b, s4[1][nt]);
      }

    // softmax -> packed P into chunk (q rows overwritten; q lives in qf regs)
    #pragma unroll
    for (int h = 0; h < 2; ++h)
      #pragma unroll
      for (int r = 0; r < 4; ++r) {
        float rs = 0.f;
        #pragma unroll
        for (int nt = 0; nt < 4; ++nt) { float e = __expf(s4[h][nt][r]); s4[h][nt][r] = e; rs += e; }
        rs = sum16(rs);
        float inv = __builtin_amdgcn_rcpf(rs);
        st4c(h * 16 + row4 + r,
             s4[h][0][r] * inv, s4[h][1][r] * inv, s4[h][2][r] * inv, s4[h][3][r] * inv);
      }

    // PV for both halves off one B-frag load
    bf16x8 pf[2][2];
    #pragma unroll
    for (int h = 0; h < 2; ++h) {
      pf[h][0] = ldCh(h * 16 + l16, quad * 8);
      pf[h][1] = ldCh(h * 16 + l16, 32 + quad * 8);
    }
    f32x4 pv[2][4];
    #pragma unroll
    for (int h = 0; h < 2; ++h)
      #pragma unroll
      for (int nt = 0; nt < 4; ++nt) pv[h][nt] = vzero;
    #pragma unroll
    for (int kk = 0; kk < 2; ++kk)
      #pragma unroll
      for (int nt = 0; nt < 4; ++nt) {
        bf16x8 b = *(const bf16x8*)(VT + (((hd * 2 + kk) * 4 + nt) * 64 + lane) * 8);
        pv[0][nt] = MFMA16(pf[0][kk], b, pv[0][nt]);
        pv[1][nt] = MFMA16(pf[1][kk], b, pv[1][nt]);
      }

    // mix/conf scale; fast tier initializes oa, deep tier accumulates
    #pragma unroll
    for (int h = 0; h < 2; ++h)
      #pragma unroll
      for (int r = 0; r < 4; ++r) {
        int Rb = rb + h * 16 + row4 + r;
        float m_ = (tier == 0) ? sA[Rb] : sB[Rb];
        #pragma unroll
        for (int nt = 0; nt < 4; ++nt) {
          if (tier == 0) oa[h][nt][r] = m_ * pv[h][nt][r];
          else           oa[h][nt][r] += m_ * pv[h][nt][r];
        }
      }
  }

  // retire out_pre into Y (Y reads all completed before bar3)
  #pragma unroll
  for (int h = 0; h < 2; ++h)
    #pragma unroll
    for (int r = 0; r < 4; ++r)
      st4y(rb + h * 16 + row4 + r, hd * 64, oa[h][0][r], oa[h][1][r], oa[h][2][r], oa[h][3][r]);
  __syncthreads();  // bar5: out_pre complete

  // ===== final GEMM (Wo) on Y: wave w -> cols w*16..+15, rows 0..127 =====
  {
    f32x4 o[8];
    #pragma unroll
    for (int mt = 0; mt < 8; ++mt) o[mt] = vzero;
    #pragma unroll
    for (int kk = 0; kk < 8; ++kk) {
      int kb = kk * 32 + quad * 8;
      bf16x8 b = wfrag(OFF_WO, w, kk);
      #pragma unroll
      for (int mt = 0; mt < 8; ++mt) {
        bf16x8 a = ldA(Yb, mt * 16 + l16, kb);
        o[mt] = MFMA16(a, b, o[mt]);
      }
    }
    float* dst = outp + (size_t)blk * 32768;
    #pragma unroll
    for (int mt = 0; mt < 8; ++mt)
      #pragma unroll
      for (int r = 0; r < 4; ++r)
        dst[(mt * 16 + row4 + r) * 256 + w * 16 + l16] = o[mt][r] + bov;
  }
}

extern "C" void kernel_launch(void* const* d_in, const int* in_sizes, int n_in,
                              void* d_out, int out_size, void* d_ws, size_t ws_size,
                              hipStream_t stream) {
  const float* query   = (const float*)d_in[0];
  const float* context = (const float*)d_in[1];
  const float* fk      = (const float*)d_in[2];
  const float* fv      = (const float*)d_in[3];
  const float* dk      = (const float*)d_in[4];
  const float* dv      = (const float*)d_in[5];
  const float* Wq      = (const float*)d_in[6];
  const float* bq      = (const float*)d_in[7];
  const float* Wg      = (const float*)d_in[8];
  const float* bg      = (const float*)d_in[9];
  const float* Wc1     = (const float*)d_in[10];
  const float* bc1     = (const float*)d_in[11];
  const float* Wc2     = (const float*)d_in[12];
  const float* bc2     = (const float*)d_in[13];
  const float* Wo      = (const float*)d_in[14];
  const float* bo      = (const float*)d_in[15];
  // d_in[16] Ws, d_in[17] bs: dead code (surprise is deleted)
  const float* mixl    = (const float*)d_in[18];
  u16* ws = (u16*)d_ws;
  float* outp = (float*)d_out;

  k_prep<<<368, 256, 0, stream>>>(Wq, Wg, Wc1, Wo, fk, fv, dk, dv, ws);
  k_fused<<<512, 1024, 152576, stream>>>(query, context, bq, bg, bc1, Wc2, bc2, bo,
                                         mixl, ws, outp);
}